// Round 17
// baseline (605.471 us; speedup 1.0000x reference)
//
#include <hip/hip_runtime.h>
#include <hip/hip_bf16.h>

#define LBUF 131072
#define TF   130048
#define TB   64

typedef short bf16x8 __attribute__((ext_vector_type(8)));
typedef float f32x4  __attribute__((ext_vector_type(4)));

__device__ __forceinline__ float ftanh(float x) {
  float ax = fminf(fabsf(x), 15.0f);
  float t  = __expf(2.0f * ax);
  float r  = 1.0f - 2.0f / (t + 1.0f);
  return copysignf(r, x);
}
__device__ __forceinline__ unsigned short b16(float f) {
  return __builtin_bit_cast(unsigned short, __float2bfloat16(f));
}
__device__ __forceinline__ float bf2f(unsigned short h) {
  return __builtin_bit_cast(float, ((unsigned)h) << 16);
}

// Pre-pack all weights into split hi/lo bf16 planes (once per call).
// Conv planes use k' = tap*32 + c (left half k'<32, right half k'>=32).
__global__ __launch_bounds__(256) void k_pack(
    const float* __restrict__ wf, const float* __restrict__ wg,
    const float* __restrict__ wr, const float* __restrict__ wsk,
    const float* __restrict__ w1, const float* __restrict__ w2,
    unsigned short* __restrict__ whp, unsigned short* __restrict__ w2p,
    unsigned short* __restrict__ w1p, unsigned short* __restrict__ w2fp)
{
  int i = blockIdx.x * 256 + threadIdx.x;
  if (i < 81920) {                       // conv weights: 20 x 4096
    int l = i >> 12, r = i & 4095;
    int m = r >> 6, k = r & 63;
    int c = k & 31, tap = k >> 5;
    float v = (m < 32) ? wf[l * 2048 + m * 64 + c * 2 + tap]
                       : wg[l * 2048 + (m - 32) * 64 + c * 2 + tap];
    unsigned short h = b16(v);
    whp[l * 8192 + m * 128 + k]      = h;
    whp[l * 8192 + m * 128 + 64 + k] = b16(v - bf2f(h));
  } else if (i < 112640) {               // 1x1 weights: 20 x 1536
    int t = i - 81920;
    int l = t / 1536, r = t - l * 1536;
    int m = r >> 5, o = r & 31;
    float v = (m < 32) ? wr[l * 1024 + m * 32 + o] : wsk[l * 512 + (m - 32) * 32 + o];
    unsigned short h = b16(v);
    w2p[l * 3072 + m * 64 + o]      = h;
    w2p[l * 3072 + m * 64 + 32 + o] = b16(v - bf2f(h));
  } else if (i < 116736) {               // W1: 4096
    int t = i - 112640;
    int q = t >> 4, k = t & 15;
    float v = w1[q * 16 + k];
    unsigned short h = b16(v);
    w1p[q * 32 + k]      = h;
    w1p[q * 32 + 16 + k] = b16(v - bf2f(h));
  } else {                               // W2: 65536
    int t = i - 116736;
    int q = t >> 8, k = t & 255;
    float v = w2[q * 256 + k];
    unsigned short h = b16(v);
    w2fp[q * 512 + k]       = h;
    w2fp[q * 512 + 256 + k] = b16(v - bf2f(h));
  }
}

// One dilated layer (round-16 k_layer + rawin folding + first flag).
// Gate staged hi-only: GEMM2 = (W_hi + W_lo) x g_hi (2 MFMAs), g bf16-rounded.
__global__ __launch_bounds__(256) void k_layer(
    const float* __restrict__ xin, float* __restrict__ xout,
    float* __restrict__ skip,
    const unsigned* __restrict__ wsrc,        // packed conv w, 4096 u32
    const unsigned short* __restrict__ w2p,   // packed 1x1, [48][64]
    const float* __restrict__ rawin, const float* __restrict__ w_init,
    int Tn, int Told, int d, int pad, int off_s, int first, int writex)
{
  __shared__ alignas(16) char xs[16384];   // [64 col][256B: Lhi|Rhi|Llo|Rlo] ^((col&15)<<4)
  __shared__ alignas(16) char gs[8192];    // [64 col][128B: hi| (lo unused)] ^((col&7)<<4)
  __shared__ alignas(16) char wbuf[16384]; // [64 m][256B hi|lo] ^((m&15)<<4); later OutS
  float (*OutS)[68] = (float (*)[68])&wbuf[0];

  int tid = threadIdx.x;
  int jb  = blockIdx.x * TB;
  int lane = tid & 63, w = tid >> 6;
  int lr = lane & 15, lg = lane >> 4;

  // 1x1 fragments from packed global (L1/L2-hot)
  bf16x8 a2h[3], a2l[3];
#pragma unroll
  for (int mt = 0; mt < 3; ++mt) {
    int m = mt * 16 + lr;
    a2h[mt] = *(const bf16x8*)(w2p + m * 64 + lg * 8);
    a2l[mt] = *(const bf16x8*)(w2p + m * 64 + 32 + lg * 8);
  }

  // conv weights: pure u32 copies into swizzled LDS
  for (int i = tid; i < 4096; i += 256) {
    int m = i >> 6, j = i & 63;
    *(unsigned*)(wbuf + ((m * 256 + j * 4) ^ ((m & 15) << 4))) = wsrc[i];
  }
  // X tile: fp32 -> split bf16 (layer 0: on-the-fly init conv)
  for (int i = tid; i < 2048; i += 256) {
    int col = i & 63, c = i >> 6;
    int e0 = jb + col - pad, e1 = e0 + d;
    float v0, v1;
    if (rawin) {
      float s = w_init[c];
      v0 = (e0 >= 0 && e0 < Told) ? s * rawin[e0] : 0.f;
      v1 = (e1 < Told) ? s * rawin[e1] : 0.f;
    } else {
      v0 = (e0 >= 0 && e0 < Told) ? xin[(size_t)c * LBUF + e0] : 0.f;
      v1 = (e1 < Told) ? xin[(size_t)c * LBUF + e1] : 0.f;
    }
    unsigned short h0 = b16(v0), l0 = b16(v0 - bf2f(h0));
    unsigned short h1 = b16(v1), l1 = b16(v1 - bf2f(h1));
    unsigned sw = (unsigned)(col & 15) << 4;
    *(unsigned short*)(xs + ((col * 256 +       c * 2) ^ sw)) = h0;
    *(unsigned short*)(xs + ((col * 256 +  64 + c * 2) ^ sw)) = h1;
    *(unsigned short*)(xs + ((col * 256 + 128 + c * 2) ^ sw)) = l0;
    *(unsigned short*)(xs + ((col * 256 + 192 + c * 2) ^ sw)) = l1;
  }
  __syncthreads();

  int col = w * 16 + lr;
  unsigned swx = (unsigned)lr << 4;

  // ---- GEMM1: K=64, 3-term split ----
  f32x4 acc1[4];
#pragma unroll
  for (int mt = 0; mt < 4; ++mt) acc1[mt] = (f32x4){0.f, 0.f, 0.f, 0.f};
#pragma unroll
  for (int ks = 0; ks < 2; ++ks) {
    bf16x8 bh = *(const bf16x8*)(xs + ((col * 256 + ks * 64 + lg * 16) ^ swx));
    bf16x8 bl = *(const bf16x8*)(xs + ((col * 256 + 128 + ks * 64 + lg * 16) ^ swx));
#pragma unroll
    for (int mt = 0; mt < 4; ++mt) {
      int row = mt * 16 + lr;
      bf16x8 ah = *(const bf16x8*)(wbuf + ((row * 256 + ks * 64 + lg * 16) ^ swx));
      bf16x8 al = *(const bf16x8*)(wbuf + ((row * 256 + 128 + ks * 64 + lg * 16) ^ swx));
      acc1[mt] = __builtin_amdgcn_mfma_f32_16x16x32_bf16(ah, bh, acc1[mt], 0, 0, 0);
      acc1[mt] = __builtin_amdgcn_mfma_f32_16x16x32_bf16(ah, bl, acc1[mt], 0, 0, 0);
      acc1[mt] = __builtin_amdgcn_mfma_f32_16x16x32_bf16(al, bh, acc1[mt], 0, 0, 0);
    }
  }

  // ---- gate -> gs (hi only, wave-local) ----
  unsigned swg = (unsigned)(col & 7) << 4;
#pragma unroll
  for (int t = 0; t < 2; ++t) {
    float g0 = ftanh(acc1[t][0]) * ftanh(acc1[t + 2][0]);
    float g1 = ftanh(acc1[t][1]) * ftanh(acc1[t + 2][1]);
    float g2 = ftanh(acc1[t][2]) * ftanh(acc1[t + 2][2]);
    float g3 = ftanh(acc1[t][3]) * ftanh(acc1[t + 2][3]);
    unsigned short h0 = b16(g0), h1 = b16(g1), h2 = b16(g2), h3 = b16(g3);
    int ob = (t * 16 + lg * 4) * 2;
    *(unsigned*)(gs + ((col * 128 + ob) ^ swg))     = (unsigned)h0 | ((unsigned)h1 << 16);
    *(unsigned*)(gs + ((col * 128 + ob + 4) ^ swg)) = (unsigned)h2 | ((unsigned)h3 << 16);
  }

  // ---- GEMM2: K=32, 2-term (full-precision W x bf16 g); wave-local B ----
  f32x4 acc2[3];
  {
    bf16x8 bgh = *(const bf16x8*)(gs + ((col * 128 + lg * 16) ^ swg));
#pragma unroll
    for (int mt = 0; mt < 3; ++mt) {
      f32x4 z = {0.f, 0.f, 0.f, 0.f};
      z = __builtin_amdgcn_mfma_f32_16x16x32_bf16(a2h[mt], bgh, z, 0, 0, 0);
      acc2[mt] = __builtin_amdgcn_mfma_f32_16x16x32_bf16(a2l[mt], bgh, z, 0, 0, 0);
    }
  }

  __syncthreads();   // Ws reads done -> reuse wbuf as OutS
  {
#pragma unroll
    for (int mt = 0; mt < 2; ++mt)
#pragma unroll
      for (int i = 0; i < 4; ++i) {
        int m = mt * 16 + lg * 4 + i;
        unsigned short xh = *(unsigned short*)(xs + ((col * 256 + 64 + m * 2) ^ swx));
        unsigned short xl = *(unsigned short*)(xs + ((col * 256 + 192 + m * 2) ^ swx));
        OutS[m][col] = acc2[mt][i] + (bf2f(xh) + bf2f(xl));
      }
#pragma unroll
    for (int i = 0; i < 4; ++i)
      OutS[32 + lg * 4 + i][col] = acc2[2][i];
  }
  __syncthreads();

  bool fullN = (jb + TB <= Tn);
  if (writex) {
    if (fullN) {
      int r = tid >> 3, cb = (tid & 7) * 8;
      size_t base = (size_t)r * LBUF + jb + cb;
      *(float4*)&xout[base]     = *(float4*)&OutS[r][cb];
      *(float4*)&xout[base + 4] = *(float4*)&OutS[r][cb + 4];
    } else {
      int c = tid & 63, r0 = tid >> 6;
      int j = jb + c;
      if (j < Tn)
#pragma unroll
        for (int rr = r0; rr < 32; rr += 4)
          xout[(size_t)rr * LBUF + j] = OutS[rr][c];
    }
  }
  if (fullN && ((off_s & 3) == 0) && jb >= off_s) {
    int r = tid >> 4, cb = (tid & 15) * 4;
    size_t base = (size_t)r * TF + (jb - off_s) + cb;
    float4 v = *(float4*)&OutS[32 + r][cb];
    if (first) {
      *(float4*)&skip[base] = v;
    } else {
      float4 o = *(const float4*)&skip[base];
      o.x += v.x; o.y += v.y; o.z += v.z; o.w += v.w;
      *(float4*)&skip[base] = o;
    }
  } else {
    int c = tid & 63, r0 = tid >> 6;
    int j = jb + c, js = j - off_s;
    if (j < Tn && js >= 0) {
#pragma unroll
      for (int rr = r0; rr < 16; rr += 4) {
        if (first) skip[(size_t)rr * TF + js]  = OutS[32 + rr][c];
        else       skip[(size_t)rr * TF + js] += OutS[32 + rr][c];
      }
    }
  }
}

// Fused final MLP (round-15 version, unchanged — measured 96 us).
__global__ __launch_bounds__(256) void k_final(
    const float* __restrict__ skip,
    const unsigned short* __restrict__ w1p,
    const unsigned short* __restrict__ w2fp,
    float* __restrict__ out)
{
  __shared__ alignas(16) char smem[49152];
  char* sks = smem;
  char* w2s = smem;
  char* h1s = smem + 16384;
  float (*OutSq)[66] = (float (*)[66])&smem[0];

  int tid = threadIdx.x;
  int jb  = blockIdx.x * 64;
  int lane = tid & 63, w = tid >> 6;
  int lr = lane & 15, lg = lane >> 4;
  int col = w * 16 + lr;

  for (int i = tid; i < 1024; i += 256) {
    int c = i & 63, k2 = i >> 6;
    float v0 = (2 * k2 < 16)     ? fmaxf(skip[(size_t)(2 * k2) * TF + jb + c], 0.f) : 0.f;
    float v1 = (2 * k2 + 1 < 16) ? fmaxf(skip[(size_t)(2 * k2 + 1) * TF + jb + c], 0.f) : 0.f;
    unsigned short h0 = b16(v0), h1 = b16(v1);
    unsigned short l0 = b16(v0 - bf2f(h0)), l1 = b16(v1 - bf2f(h1));
    unsigned sw = (unsigned)(c & 7) << 4;
    *(unsigned*)(sks + ((c * 128 + k2 * 4) ^ sw))      = (unsigned)h0 | ((unsigned)h1 << 16);
    *(unsigned*)(sks + ((c * 128 + 64 + k2 * 4) ^ sw)) = (unsigned)l0 | ((unsigned)l1 << 16);
  }
  __syncthreads();

  unsigned swk = (unsigned)(col & 7) << 4;
  unsigned swh = (unsigned)(col & 31) << 4;

  {
    bf16x8 bh = *(const bf16x8*)(sks + ((col * 128 + lg * 16) ^ swk));
    bf16x8 bl = *(const bf16x8*)(sks + ((col * 128 + 64 + lg * 16) ^ swk));
#pragma unroll
    for (int mt = 0; mt < 16; ++mt) {
      bf16x8 ah = {0, 0, 0, 0, 0, 0, 0, 0};
      bf16x8 al = {0, 0, 0, 0, 0, 0, 0, 0};
      if (lg < 2) {
        int m = mt * 16 + lr;
        ah = *(const bf16x8*)(w1p + m * 32 + lg * 8);
        al = *(const bf16x8*)(w1p + m * 32 + 16 + lg * 8);
      }
      f32x4 z = {0.f, 0.f, 0.f, 0.f};
      z = __builtin_amdgcn_mfma_f32_16x16x32_bf16(ah, bh, z, 0, 0, 0);
      z = __builtin_amdgcn_mfma_f32_16x16x32_bf16(ah, bl, z, 0, 0, 0);
      z = __builtin_amdgcn_mfma_f32_16x16x32_bf16(al, bh, z, 0, 0, 0);
      int qb = (mt * 16 + lg * 4) * 2;
      unsigned p01 = (unsigned)b16(fmaxf(z[0], 0.f)) | ((unsigned)b16(fmaxf(z[1], 0.f)) << 16);
      unsigned p23 = (unsigned)b16(fmaxf(z[2], 0.f)) | ((unsigned)b16(fmaxf(z[3], 0.f)) << 16);
      *(unsigned*)(h1s + ((col * 512 + qb) ^ swh))     = p01;
      *(unsigned*)(h1s + ((col * 512 + qb + 4) ^ swh)) = p23;
    }
  }

  f32x4 acco[16];
#pragma unroll
  for (int mt = 0; mt < 16; ++mt) acco[mt] = (f32x4){0.f, 0.f, 0.f, 0.f};

  for (int kb = 0; kb < 8; ++kb) {
    __syncthreads();
    for (int i = tid; i < 1024; i += 256) {
      int q = i >> 2, part = i & 3;
      uint4 v = *(const uint4*)(w2fp + q * 512 + kb * 32 + part * 8);
      *(uint4*)(w2s + ((q * 64 + part * 16) ^ ((q & 7) << 4))) = v;
    }
    __syncthreads();
    bf16x8 bh = *(const bf16x8*)(h1s + ((col * 512 + kb * 64 + lg * 16) ^ swh));
#pragma unroll
    for (int mt = 0; mt < 16; ++mt) {
      int row = mt * 16 + lr;
      bf16x8 ah = *(const bf16x8*)(w2s + ((row * 64 + lg * 16) ^ ((row & 7) << 4)));
      acco[mt] = __builtin_amdgcn_mfma_f32_16x16x32_bf16(ah, bh, acco[mt], 0, 0, 0);
    }
  }

#pragma unroll
  for (int p = 0; p < 4; ++p) {
    __syncthreads();
#pragma unroll
    for (int mq = 0; mq < 4; ++mq)
#pragma unroll
      for (int i = 0; i < 4; ++i)
        OutSq[mq * 16 + lg * 4 + i][col] = acco[p * 4 + mq][i];
    __syncthreads();
    int r = tid >> 2, cb = (tid & 3) * 16;
    size_t base = (size_t)(p * 64 + r) * TF + jb + cb;
#pragma unroll
    for (int v = 0; v < 4; ++v)
      *(float4*)&out[base + v * 4] = *(float4*)&OutSq[r][cb + v * 4];
  }
}

extern "C" void kernel_launch(void* const* d_in, const int* in_sizes, int n_in,
                              void* d_out, int out_size, void* d_ws, size_t ws_size,
                              hipStream_t stream) {
  const float* x_in     = (const float*)d_in[0];
  const float* w_init   = (const float*)d_in[1];
  const float* w_filter = (const float*)d_in[2];
  const float* w_gate   = (const float*)d_in[3];
  const float* w_res    = (const float*)d_in[4];
  const float* w_skip   = (const float*)d_in[5];
  const float* w_f1     = (const float*)d_in[6];
  const float* w_f2     = (const float*)d_in[7];
  float* out = (float*)d_out;

  float* xa    = (float*)d_ws;
  float* xb    = xa + 32 * (size_t)LBUF;
  float* skipb = xb + 32 * (size_t)LBUF;
  unsigned short* whp  = (unsigned short*)(skipb + 16 * (size_t)TF);
  unsigned short* w2p  = whp + 20 * 8192;
  unsigned short* w1p  = w2p + 20 * 3072;
  unsigned short* w2fp = w1p + 8192;

  k_pack<<<712, 256, 0, stream>>>(w_filter, w_gate, w_res, w_skip, w_f1, w_f2,
                                  whp, w2p, w1p, w2fp);

  int T = LBUF;
  for (int idx = 0; idx < 20; ++idx) {
    int d    = 1 << (idx % 10);
    int pad  = (d - (T % d)) % d;
    int Tn   = T + pad - d;
    int offs = Tn - TF;
    k_layer<<<(Tn + TB - 1) / TB, 256, 0, stream>>>(
        xa, xb, skipb,
        (const unsigned*)(whp + (size_t)idx * 8192), w2p + (size_t)idx * 3072,
        (idx == 0) ? x_in : nullptr, w_init,
        Tn, T, d, pad, offs, (idx == 0) ? 1 : 0, (idx == 19) ? 0 : 1);
    float* t = xa; xa = xb; xb = t;
    T = Tn;
  }

  k_final<<<TF / 64, 256, 0, stream>>>(skipb, w1p, w2fp, out);
}

// Round 18
// 499.162 us; speedup vs baseline: 1.2130x; 1.2130x over previous
//
#include <hip/hip_runtime.h>
#include <hip/hip_bf16.h>

#define LBUF 131072
#define TF   130048
#define TB   64

typedef short bf16x8 __attribute__((ext_vector_type(8)));
typedef float f32x4  __attribute__((ext_vector_type(4)));

__device__ __forceinline__ float ftanh(float x) {
  float ax = fminf(fabsf(x), 15.0f);
  float t  = __expf(2.0f * ax);
  float r  = 1.0f - 2.0f / (t + 1.0f);
  return copysignf(r, x);
}
__device__ __forceinline__ unsigned short b16(float f) {
  return __builtin_bit_cast(unsigned short, __float2bfloat16(f));
}
__device__ __forceinline__ float bf2f(unsigned short h) {
  return __builtin_bit_cast(float, ((unsigned)h) << 16);
}
__device__ __forceinline__ unsigned long long packhl2(float a, float b,
                                                      unsigned long long* lo) {
  unsigned short ha = b16(a), hb = b16(b);
  unsigned short la = b16(a - bf2f(ha)), lb = b16(b - bf2f(hb));
  *lo = (unsigned long long)la | ((unsigned long long)lb << 16);
  return (unsigned long long)ha | ((unsigned long long)hb << 16);
}

// Pre-pack all weights into split hi/lo bf16 planes (once per call).
// Conv planes use k' = tap*32 + c.
__global__ __launch_bounds__(256) void k_pack(
    const float* __restrict__ wf, const float* __restrict__ wg,
    const float* __restrict__ wr, const float* __restrict__ wsk,
    const float* __restrict__ w1, const float* __restrict__ w2,
    unsigned short* __restrict__ whp, unsigned short* __restrict__ w2p,
    unsigned short* __restrict__ w1p, unsigned short* __restrict__ w2fp)
{
  int i = blockIdx.x * 256 + threadIdx.x;
  if (i < 81920) {                       // conv weights: 20 x 4096
    int l = i >> 12, r = i & 4095;
    int m = r >> 6, k = r & 63;
    int c = k & 31, tap = k >> 5;
    float v = (m < 32) ? wf[l * 2048 + m * 64 + c * 2 + tap]
                       : wg[l * 2048 + (m - 32) * 64 + c * 2 + tap];
    unsigned short h = b16(v);
    whp[l * 8192 + m * 128 + k]      = h;
    whp[l * 8192 + m * 128 + 64 + k] = b16(v - bf2f(h));
  } else if (i < 112640) {               // 1x1 weights: 20 x 1536
    int t = i - 81920;
    int l = t / 1536, r = t - l * 1536;
    int m = r >> 5, o = r & 31;
    float v = (m < 32) ? wr[l * 1024 + m * 32 + o] : wsk[l * 512 + (m - 32) * 32 + o];
    unsigned short h = b16(v);
    w2p[l * 3072 + m * 64 + o]      = h;
    w2p[l * 3072 + m * 64 + 32 + o] = b16(v - bf2f(h));
  } else if (i < 116736) {               // W1: 4096
    int t = i - 112640;
    int q = t >> 4, k = t & 15;
    float v = w1[q * 16 + k];
    unsigned short h = b16(v);
    w1p[q * 32 + k]      = h;
    w1p[q * 32 + 16 + k] = b16(v - bf2f(h));
  } else {                               // W2: 65536
    int t = i - 116736;
    int q = t >> 8, k = t & 255;
    float v = w2[q * 256 + k];
    unsigned short h = b16(v);
    w2fp[q * 512 + k]       = h;
    w2fp[q * 512 + 256 + k] = b16(v - bf2f(h));
  }
}

// One dilated layer. x/skip are TIME-MAJOR: x[j][32], skip[j][16].
// Single barrier; epilogue writes straight from MFMA registers (aligned float4s).
__global__ __launch_bounds__(256) void k_layer(
    const float* __restrict__ xin, float* __restrict__ xout,
    float* __restrict__ skip,
    const unsigned* __restrict__ wsrc,        // packed conv w, 4096 u32
    const unsigned short* __restrict__ w2p,   // packed 1x1, [48][64]
    const float* __restrict__ rawin, const float* __restrict__ w_init,
    int Tn, int Told, int d, int pad, int off_s, int first, int writex)
{
  __shared__ alignas(16) char xs[16384];   // [64 col][256B: Lhi|Rhi|Llo|Rlo] ^((col&15)<<4)
  __shared__ alignas(16) char gs[8192];    // [64 col][128B: hi|lo] ^((col&7)<<4)
  __shared__ alignas(16) char wbuf[16384]; // [64 m][256B hi|lo] ^((m&15)<<4)

  int tid = threadIdx.x;
  int jb  = blockIdx.x * TB;
  int lane = tid & 63, w = tid >> 6;
  int lr = lane & 15, lg = lane >> 4;

  // 1x1 fragments from packed global (L1/L2-hot)
  bf16x8 a2h[3], a2l[3];
#pragma unroll
  for (int mt = 0; mt < 3; ++mt) {
    int m = mt * 16 + lr;
    a2h[mt] = *(const bf16x8*)(w2p + m * 64 + lg * 8);
    a2l[mt] = *(const bf16x8*)(w2p + m * 64 + 32 + lg * 8);
  }

  // conv weights: pure u32 copies into swizzled LDS
  for (int i = tid; i < 4096; i += 256) {
    int m = i >> 6, j = i & 63;
    *(unsigned*)(wbuf + ((m * 256 + j * 4) ^ ((m & 15) << 4))) = wsrc[i];
  }
  // X staging: vectorized along channels (quad = 4 c's of one col, uniform bounds)
#pragma unroll
  for (int it = 0; it < 2; ++it) {
    int qi = tid + it * 256;          // 0..511
    int col = qi >> 3, c4 = (qi & 7) * 4;
    int e0 = jb + col - pad, e1 = e0 + d;
    float4 L = {0.f, 0.f, 0.f, 0.f}, R = {0.f, 0.f, 0.f, 0.f};
    if (rawin) {
      float4 s = *(const float4*)&w_init[c4];
      if (e0 >= 0 && e0 < Told) {
        float v = rawin[e0];
        L = (float4){s.x * v, s.y * v, s.z * v, s.w * v};
      }
      if (e1 < Told) {
        float v = rawin[e1];
        R = (float4){s.x * v, s.y * v, s.z * v, s.w * v};
      }
    } else {
      if (e0 >= 0 && e0 < Told) L = *(const float4*)&xin[(size_t)e0 * 32 + c4];
      if (e1 < Told)            R = *(const float4*)&xin[(size_t)e1 * 32 + c4];
    }
    unsigned long long lhl, rhl;
    unsigned long long lh0, rh0;
    unsigned long long tmp;
    // pack 4 values per tap into u64 hi + u64 lo (u16 lanes)
    unsigned long long Lhi, Llo, Rhi, Rlo;
    {
      unsigned long long lo01, lo23, hi01, hi23;
      hi01 = packhl2(L.x, L.y, &lo01);
      hi23 = packhl2(L.z, L.w, &lo23);
      Lhi = hi01 | (hi23 << 32); Llo = lo01 | (lo23 << 32);
      hi01 = packhl2(R.x, R.y, &lo01);
      hi23 = packhl2(R.z, R.w, &lo23);
      Rhi = hi01 | (hi23 << 32); Rlo = lo01 | (lo23 << 32);
    }
    (void)lhl; (void)rhl; (void)lh0; (void)rh0; (void)tmp;
    unsigned sw = (unsigned)(col & 15) << 4;
    int base = col * 256 + c4 * 2;
    *(unsigned long long*)(xs + ((base) ^ sw))       = Lhi;
    *(unsigned long long*)(xs + ((base + 64) ^ sw))  = Rhi;
    *(unsigned long long*)(xs + ((base + 128) ^ sw)) = Llo;
    *(unsigned long long*)(xs + ((base + 192) ^ sw)) = Rlo;
  }
  __syncthreads();

  int col = w * 16 + lr;
  unsigned swx = (unsigned)lr << 4;

  // ---- GEMM1: K=64, 3-term split ----
  f32x4 acc1[4];
#pragma unroll
  for (int mt = 0; mt < 4; ++mt) acc1[mt] = (f32x4){0.f, 0.f, 0.f, 0.f};
#pragma unroll
  for (int ks = 0; ks < 2; ++ks) {
    bf16x8 bh = *(const bf16x8*)(xs + ((col * 256 + ks * 64 + lg * 16) ^ swx));
    bf16x8 bl = *(const bf16x8*)(xs + ((col * 256 + 128 + ks * 64 + lg * 16) ^ swx));
#pragma unroll
    for (int mt = 0; mt < 4; ++mt) {
      int row = mt * 16 + lr;
      bf16x8 ah = *(const bf16x8*)(wbuf + ((row * 256 + ks * 64 + lg * 16) ^ swx));
      bf16x8 al = *(const bf16x8*)(wbuf + ((row * 256 + 128 + ks * 64 + lg * 16) ^ swx));
      acc1[mt] = __builtin_amdgcn_mfma_f32_16x16x32_bf16(ah, bh, acc1[mt], 0, 0, 0);
      acc1[mt] = __builtin_amdgcn_mfma_f32_16x16x32_bf16(ah, bl, acc1[mt], 0, 0, 0);
      acc1[mt] = __builtin_amdgcn_mfma_f32_16x16x32_bf16(al, bh, acc1[mt], 0, 0, 0);
    }
  }

  // ---- gate -> gs split hi/lo (wave-local) ----
  unsigned swg = (unsigned)(col & 7) << 4;
#pragma unroll
  for (int t = 0; t < 2; ++t) {
    float g0 = ftanh(acc1[t][0]) * ftanh(acc1[t + 2][0]);
    float g1 = ftanh(acc1[t][1]) * ftanh(acc1[t + 2][1]);
    float g2 = ftanh(acc1[t][2]) * ftanh(acc1[t + 2][2]);
    float g3 = ftanh(acc1[t][3]) * ftanh(acc1[t + 2][3]);
    unsigned long long lo01, lo23;
    unsigned long long hi01 = packhl2(g0, g1, &lo01);
    unsigned long long hi23 = packhl2(g2, g3, &lo23);
    int ob = (t * 16 + lg * 4) * 2;
    *(unsigned long long*)(gs + ((col * 128 + ob) ^ swg))      = hi01 | (hi23 << 32);
    *(unsigned long long*)(gs + ((col * 128 + 64 + ob) ^ swg)) = lo01 | (lo23 << 32);
  }

  // ---- GEMM2: K=32, 3-term, A regs; wave-local B ----
  f32x4 acc2[3];
  {
    bf16x8 bgh = *(const bf16x8*)(gs + ((col * 128 + lg * 16) ^ swg));
    bf16x8 bgl = *(const bf16x8*)(gs + ((col * 128 + 64 + lg * 16) ^ swg));
#pragma unroll
    for (int mt = 0; mt < 3; ++mt) {
      f32x4 z = {0.f, 0.f, 0.f, 0.f};
      z = __builtin_amdgcn_mfma_f32_16x16x32_bf16(a2h[mt], bgh, z, 0, 0, 0);
      z = __builtin_amdgcn_mfma_f32_16x16x32_bf16(a2h[mt], bgl, z, 0, 0, 0);
      acc2[mt] = __builtin_amdgcn_mfma_f32_16x16x32_bf16(a2l[mt], bgh, z, 0, 0, 0);
    }
  }

  // ---- epilogue: direct register stores (time-major, aligned float4) ----
  int j = jb + col;
  if (writex && j < Tn) {
#pragma unroll
    for (int mt = 0; mt < 2; ++mt) {
      float4 v;
#pragma unroll
      for (int i = 0; i < 4; ++i) {
        int m = mt * 16 + lg * 4 + i;
        unsigned short xh = *(unsigned short*)(xs + ((col * 256 + 64 + m * 2) ^ swx));
        unsigned short xl = *(unsigned short*)(xs + ((col * 256 + 192 + m * 2) ^ swx));
        float r = acc2[mt][i] + (bf2f(xh) + bf2f(xl));
        if (i == 0) v.x = r; else if (i == 1) v.y = r; else if (i == 2) v.z = r; else v.w = r;
      }
      *(float4*)&xout[(size_t)j * 32 + mt * 16 + lg * 4] = v;
    }
  }
  int js = j - off_s;
  if (j < Tn && js >= 0) {
    float4 v = {acc2[2][0], acc2[2][1], acc2[2][2], acc2[2][3]};
    float* sp = skip + (size_t)js * 16 + lg * 4;
    if (first) {
      *(float4*)sp = v;
    } else {
      float4 o = *(const float4*)sp;
      o.x += v.x; o.y += v.y; o.z += v.z; o.w += v.w;
      *(float4*)sp = o;
    }
  }
}

// Fused final MLP (R15 structure; skip now TIME-MAJOR [j][16]).
__global__ __launch_bounds__(256) void k_final(
    const float* __restrict__ skip,
    const unsigned short* __restrict__ w1p,
    const unsigned short* __restrict__ w2fp,
    float* __restrict__ out)
{
  __shared__ alignas(16) char smem[49152];
  char* sks = smem;             // [64 col][128B hi|lo] ^((col&7)<<4), 8KB
  char* w2s = smem;             // [256 q][64B hi] ^((q&7)<<4), 16KB (aliases sks)
  char* h1s = smem + 16384;     // [64 col][512B hi] ^((col&31)<<4), 32KB
  float (*OutSq)[66] = (float (*)[66])&smem[0];

  int tid = threadIdx.x;
  int jb  = blockIdx.x * 64;
  int lane = tid & 63, w = tid >> 6;
  int lr = lane & 15, lg = lane >> 4;
  int col = w * 16 + lr;

  // skip staging: 1 aligned float4 per thread (time-major), zero k>=16 region
  {
    int c = tid >> 2, k4 = (tid & 3) * 4;
    float4 v = *(const float4*)&skip[(size_t)(jb + c) * 16 + k4];
    v.x = fmaxf(v.x, 0.f); v.y = fmaxf(v.y, 0.f);
    v.z = fmaxf(v.z, 0.f); v.w = fmaxf(v.w, 0.f);
    unsigned long long lo01, lo23;
    unsigned long long hi01 = packhl2(v.x, v.y, &lo01);
    unsigned long long hi23 = packhl2(v.z, v.w, &lo23);
    unsigned sw = (unsigned)(c & 7) << 4;
    int base = c * 128 + k4 * 2;
    *(unsigned long long*)(sks + ((base) ^ sw))       = hi01 | (hi23 << 32);
    *(unsigned long long*)(sks + ((base + 64) ^ sw))  = lo01 | (lo23 << 32);
    *(unsigned long long*)(sks + ((base + 32) ^ sw))  = 0ull;   // hi k 16..31
    *(unsigned long long*)(sks + ((base + 96) ^ sw))  = 0ull;   // lo k 16..31
  }
  __syncthreads();

  unsigned swk = (unsigned)(col & 7) << 4;
  unsigned swh = (unsigned)(col & 31) << 4;

  // GEMM1 -> H1 (wave-local handoff)
  {
    bf16x8 bh = *(const bf16x8*)(sks + ((col * 128 + lg * 16) ^ swk));
    bf16x8 bl = *(const bf16x8*)(sks + ((col * 128 + 64 + lg * 16) ^ swk));
#pragma unroll
    for (int mt = 0; mt < 16; ++mt) {
      bf16x8 ah = {0, 0, 0, 0, 0, 0, 0, 0};
      bf16x8 al = {0, 0, 0, 0, 0, 0, 0, 0};
      if (lg < 2) {
        int m = mt * 16 + lr;
        ah = *(const bf16x8*)(w1p + m * 32 + lg * 8);
        al = *(const bf16x8*)(w1p + m * 32 + 16 + lg * 8);
      }
      f32x4 z = {0.f, 0.f, 0.f, 0.f};
      z = __builtin_amdgcn_mfma_f32_16x16x32_bf16(ah, bh, z, 0, 0, 0);
      z = __builtin_amdgcn_mfma_f32_16x16x32_bf16(ah, bl, z, 0, 0, 0);
      z = __builtin_amdgcn_mfma_f32_16x16x32_bf16(al, bh, z, 0, 0, 0);
      int qb = (mt * 16 + lg * 4) * 2;
      unsigned p01 = (unsigned)b16(fmaxf(z[0], 0.f)) | ((unsigned)b16(fmaxf(z[1], 0.f)) << 16);
      unsigned p23 = (unsigned)b16(fmaxf(z[2], 0.f)) | ((unsigned)b16(fmaxf(z[3], 0.f)) << 16);
      *(unsigned*)(h1s + ((col * 512 + qb) ^ swh))     = p01;
      *(unsigned*)(h1s + ((col * 512 + qb + 4) ^ swh)) = p23;
    }
  }

  // GEMM2: K=256 in 8 chunks; W2 hi-only staged into w2s (aliases sks)
  f32x4 acco[16];
#pragma unroll
  for (int mt = 0; mt < 16; ++mt) acco[mt] = (f32x4){0.f, 0.f, 0.f, 0.f};

  for (int kb = 0; kb < 8; ++kb) {
    __syncthreads();
    for (int i = tid; i < 1024; i += 256) {
      int q = i >> 2, part = i & 3;
      uint4 v = *(const uint4*)(w2fp + q * 512 + kb * 32 + part * 8);
      *(uint4*)(w2s + ((q * 64 + part * 16) ^ ((q & 7) << 4))) = v;
    }
    __syncthreads();
    bf16x8 bh = *(const bf16x8*)(h1s + ((col * 512 + kb * 64 + lg * 16) ^ swh));
#pragma unroll
    for (int mt = 0; mt < 16; ++mt) {
      int row = mt * 16 + lr;
      bf16x8 ah = *(const bf16x8*)(w2s + ((row * 64 + lg * 16) ^ ((row & 7) << 4)));
      acco[mt] = __builtin_amdgcn_mfma_f32_16x16x32_bf16(ah, bh, acco[mt], 0, 0, 0);
    }
  }

#pragma unroll
  for (int p = 0; p < 4; ++p) {
    __syncthreads();
#pragma unroll
    for (int mq = 0; mq < 4; ++mq)
#pragma unroll
      for (int i = 0; i < 4; ++i)
        OutSq[mq * 16 + lg * 4 + i][col] = acco[p * 4 + mq][i];
    __syncthreads();
    int r = tid >> 2, cb = (tid & 3) * 16;
    size_t base = (size_t)(p * 64 + r) * TF + jb + cb;
#pragma unroll
    for (int v = 0; v < 4; ++v)
      *(float4*)&out[base + v * 4] = *(float4*)&OutSq[r][cb + v * 4];
  }
}

extern "C" void kernel_launch(void* const* d_in, const int* in_sizes, int n_in,
                              void* d_out, int out_size, void* d_ws, size_t ws_size,
                              hipStream_t stream) {
  const float* x_in     = (const float*)d_in[0];
  const float* w_init   = (const float*)d_in[1];
  const float* w_filter = (const float*)d_in[2];
  const float* w_gate   = (const float*)d_in[3];
  const float* w_res    = (const float*)d_in[4];
  const float* w_skip   = (const float*)d_in[5];
  const float* w_f1     = (const float*)d_in[6];
  const float* w_f2     = (const float*)d_in[7];
  float* out = (float*)d_out;

  float* xa    = (float*)d_ws;                    // time-major [LBUF][32]
  float* xb    = xa + 32 * (size_t)LBUF;
  float* skipb = xb + 32 * (size_t)LBUF;          // time-major [TF][16]
  unsigned short* whp  = (unsigned short*)(skipb + 16 * (size_t)TF);
  unsigned short* w2p  = whp + 20 * 8192;
  unsigned short* w1p  = w2p + 20 * 3072;
  unsigned short* w2fp = w1p + 8192;

  k_pack<<<712, 256, 0, stream>>>(w_filter, w_gate, w_res, w_skip, w_f1, w_f2,
                                  whp, w2p, w1p, w2fp);

  int T = LBUF;
  for (int idx = 0; idx < 20; ++idx) {
    int d    = 1 << (idx % 10);
    int pad  = (d - (T % d)) % d;
    int Tn   = T + pad - d;
    int offs = Tn - TF;
    k_layer<<<(Tn + TB - 1) / TB, 256, 0, stream>>>(
        xa, xb, skipb,
        (const unsigned*)(whp + (size_t)idx * 8192), w2p + (size_t)idx * 3072,
        (idx == 0) ? x_in : nullptr, w_init,
        Tn, T, d, pad, offs, (idx == 0) ? 1 : 0, (idx == 19) ? 0 : 1);
    float* t = xa; xa = xb; xb = t;
    T = Tn;
  }

  k_final<<<TF / 64, 256, 0, stream>>>(skipb, w1p, w2fp, out);
}